// Round 2
// baseline (283.561 us; speedup 1.0000x reference)
//
#include <hip/hip_runtime.h>

// NoTradeRegionRNN: D=2, T=512, B=16384.
// One thread per batch column b; sequential over T (true data dependence).
// Double-buffered register prefetch of U timesteps to hide HBM latency
// (only 256 waves total -> no TLP to hide latency, must use ILP).

#define U 8

__global__ __launch_bounds__(64, 1)
void ntr_rnn_kernel(const float* __restrict__ xin,      // (2,T,B)
                    const float* __restrict__ target,   // (2)
                    const float* __restrict__ rets,     // (2,T,B)
                    const float* __restrict__ w_input,  // (2)
                    const float* __restrict__ w_hidden, // (2)
                    const float* __restrict__ b_hidden, // (2)
                    const float* __restrict__ w_fc1,    // (2)
                    const float* __restrict__ w_fc2,    // (2)
                    const float* __restrict__ w_rotate, // (2,2) row-major
                    float* __restrict__ out,            // (2,T,B) then hT (2,B)
                    int T, int B)
{
    const int b = blockIdx.x * blockDim.x + threadIdx.x;
    if (b >= B) return;

    // ---- wave-uniform scalar setup (compiler puts these in SGPRs) ----
    const float r00 = w_rotate[0], r01 = w_rotate[1];
    const float r10 = w_rotate[2], r11 = w_rotate[3];
    const float bh0 = b_hidden[0], bh1 = b_hidden[1];
    const float t0  = target[0],   t1  = target[1];

    // Corner[c] = w_rotate @ (idx[c] @ b_hidden) + target
    // idx@b_hidden: v0=(-bh0,-bh1) v1=(-bh0,+bh1) v2=(+bh0,+bh1) v3=(+bh0,-bh1)
    const float vx[4] = {-bh0, -bh0, bh0, bh0};
    const float vy[4] = {-bh1,  bh1, bh1, -bh1};
    float C[4][2];
#pragma unroll
    for (int c = 0; c < 4; ++c) {
        C[c][0] = r00 * vx[c] + r01 * vy[c] + t0;
        C[c][1] = r10 * vx[c] + r11 * vy[c] + t1;
    }
    const float ac = r10 / r00;
    const float bd = r01 / r11;
    const bool bdp = (bd >= 0.0f);
    const bool acp = (ac >= 0.0f);

    const float cbd_l    = bdp ? C[0][1] : C[1][1];
    const float k_lbx    = fabsf(C[1][0] - C[0][0]);
    const float base_lbx = bdp ? C[1][0] : C[0][0];

    const float cbd_u    = bdp ? C[3][1] : C[2][1];
    const float k_ubx    = fabsf(C[2][0] - C[3][0]);
    const float base_ubx = bdp ? C[2][0] : C[3][0];

    const float cac_l    = acp ? C[0][0] : C[3][0];
    const float k_lby    = fabsf(C[0][1] - C[3][1]);
    const float base_lby = acp ? C[3][1] : C[0][1];

    const float cac_u    = acp ? C[1][0] : C[2][0];
    const float k_uby    = fabsf(C[1][1] - C[2][1]);
    const float base_uby = acp ? C[2][1] : C[1][1];

    const float Wi0 = w_input[0],  Wi1 = w_input[1];
    const float Wh0 = w_hidden[0], Wh1 = w_hidden[1];
    const float W10 = w_fc1[0],    W11 = w_fc1[1];
    const float W20 = w_fc2[0],    W21 = w_fc2[1];

    const size_t TB = (size_t)T * B;
    const float* px0 = xin  + b;
    const float* px1 = xin  + TB + b;
    const float* pr0 = rets + b;
    const float* pr1 = rets + TB + b;
    float* po0 = out + b;
    float* po1 = out + TB + b;

    // h0 = x[:,0,:]
    float hx = px0[0];
    float hy = px1[0];
    po0[0] = hx;
    po1[0] = hy;

    // one recurrence step: h <- cell(x, adjust(h, r))
    auto step = [&](float x0, float x1, float r0, float r1) {
        float denom = fmaf(hx, r0, fmaf(hy, r1, 1.0f));
        float inv   = 1.0f / denom;
        float adjx  = hx * (1.0f + r0) * inv;
        float adjy  = hy * (1.0f + r1) * inv;
        // bounds(adj)
        float lbx = base_lbx - fmaxf(k_lbx - fmaxf((adjy - cbd_l) * bd, 0.0f), 0.0f);
        float ubx = base_ubx - fmaxf(k_ubx - fmaxf((adjy - cbd_u) * bd, 0.0f), 0.0f);
        float lby = base_lby - fmaxf(k_lby - fmaxf((adjx - cac_l) * ac, 0.0f), 0.0f);
        float uby = base_uby - fmaxf(k_uby - fmaxf((adjx - cac_u) * ac, 0.0f), 0.0f);
        // 2-layer cell
        float g1x = fmaxf(fmaf(Wi0, x0, fmaf(Wh0, adjx, -lbx)), 0.0f);
        float g1y = fmaxf(fmaf(Wi1, x1, fmaf(Wh1, adjy, -lby)), 0.0f);
        float g2x = fmaxf(fmaf(W10, g1x, ubx - lbx), 0.0f);
        float g2y = fmaxf(fmaf(W11, g1y, uby - lby), 0.0f);
        hx = fmaf(W20, g2x, ubx);
        hy = fmaf(W21, g2y, uby);
    };

    auto loadg = [&](float (&gx0)[U], float (&gx1)[U],
                     float (&gr0)[U], float (&gr1)[U], int tb) {
#pragma unroll
        for (int i = 0; i < U; ++i) {
            int t = tb + i;
            if (t < T) {
                gx0[i] = px0[(size_t)t * B];
                gx1[i] = px1[(size_t)t * B];
                gr0[i] = pr0[(size_t)(t - 1) * B];
                gr1[i] = pr1[(size_t)(t - 1) * B];
            }
        }
    };

    auto computeg = [&](float (&gx0)[U], float (&gx1)[U],
                        float (&gr0)[U], float (&gr1)[U], int tb) {
#pragma unroll
        for (int i = 0; i < U; ++i) {
            int t = tb + i;
            if (t < T) {
                step(gx0[i], gx1[i], gr0[i], gr1[i]);
                po0[(size_t)t * B] = hx;
                po1[(size_t)t * B] = hy;
            }
        }
    };

    float Ax0[U], Ax1[U], Ar0[U], Ar1[U];
    float Bx0[U], Bx1[U], Br0[U], Br1[U];

    int t = 1;
    loadg(Ax0, Ax1, Ar0, Ar1, t);
    while (true) {
        int tn = t + U;
        if (tn < T) loadg(Bx0, Bx1, Br0, Br1, tn);   // prefetch next group
        computeg(Ax0, Ax1, Ar0, Ar1, t);             // compute current group
        if (tn >= T) break;
        t = tn;
        tn = t + U;
        if (tn < T) loadg(Ax0, Ax1, Ar0, Ar1, tn);
        computeg(Bx0, Bx1, Br0, Br1, t);
        if (tn >= T) break;
        t = tn;
    }

    // hT = last h, shape (2,1,B) appended after output
    out[2 * TB + b]     = hx;
    out[2 * TB + B + b] = hy;
}

extern "C" void kernel_launch(void* const* d_in, const int* in_sizes, int n_in,
                              void* d_out, int out_size, void* d_ws, size_t ws_size,
                              hipStream_t stream) {
    const float* xin      = (const float*)d_in[0];
    const float* target   = (const float*)d_in[1];
    const float* rets     = (const float*)d_in[2];
    // d_in[3] = hidden (unused by reference)
    const float* w_input  = (const float*)d_in[4];
    const float* w_hidden = (const float*)d_in[5];
    const float* b_hidden = (const float*)d_in[6];
    const float* w_fc1    = (const float*)d_in[7];
    const float* w_fc2    = (const float*)d_in[8];
    const float* w_rotate = (const float*)d_in[9];
    float* out = (float*)d_out;

    const int B = in_sizes[3] / 2;             // hidden is (2,1,B)
    const int T = in_sizes[0] / in_sizes[3];   // input is (2,T,B)

    const int threads = 64;
    const int blocks  = (B + threads - 1) / threads;
    hipLaunchKernelGGL(ntr_rnn_kernel, dim3(blocks), dim3(threads), 0, stream,
                       xin, target, rets, w_input, w_hidden, b_hidden,
                       w_fc1, w_fc2, w_rotate, out, T, B);
}

// Round 3
// 198.350 us; speedup vs baseline: 1.4296x; 1.4296x over previous
//
#include <hip/hip_runtime.h>

// NoTradeRegionRNN: D=2, T=512, B=16384.
// One thread per batch column; sequential over T (true data dependence).
// Latency-bound (1 wave/CU, no TLP): depth-3 rotating register pipeline,
// exact 7 + 63x8 step structure (no per-element guards), raw v_rcp_f32,
// pre-folded bound constants, nontemporal output stores.

#define U 8

__global__ __launch_bounds__(64, 1)
void ntr_rnn_kernel(const float* __restrict__ xin,      // (2,T,B)
                    const float* __restrict__ target,   // (2)
                    const float* __restrict__ rets,     // (2,T,B)
                    const float* __restrict__ w_input,  // (2)
                    const float* __restrict__ w_hidden, // (2)
                    const float* __restrict__ b_hidden, // (2)
                    const float* __restrict__ w_fc1,    // (2)
                    const float* __restrict__ w_fc2,    // (2)
                    const float* __restrict__ w_rotate, // (2,2) row-major
                    float* __restrict__ out,            // (2,T,B) then hT (2,B)
                    int T, int B)
{
    const int b = blockIdx.x * blockDim.x + threadIdx.x;
    if (b >= B) return;

    // ---- wave-uniform scalar setup (SGPRs) ----
    const float r00 = w_rotate[0], r01 = w_rotate[1];
    const float r10 = w_rotate[2], r11 = w_rotate[3];
    const float bh0 = b_hidden[0], bh1 = b_hidden[1];
    const float t0  = target[0],   t1  = target[1];

    const float vx[4] = {-bh0, -bh0, bh0, bh0};
    const float vy[4] = {-bh1,  bh1, bh1, -bh1};
    float C[4][2];
#pragma unroll
    for (int c = 0; c < 4; ++c) {
        C[c][0] = r00 * vx[c] + r01 * vy[c] + t0;
        C[c][1] = r10 * vx[c] + r11 * vy[c] + t1;
    }
    const float ac = r10 / r00;
    const float bd = r01 / r11;
    const bool bdp = (bd >= 0.0f);
    const bool acp = (ac >= 0.0f);

    // bounds(h): lbx = base_lbx - relu(k_lbx - relu(hy*bd - cbd_l*bd)) etc.
    // pre-fold c*slope so the in-loop op is a single fma.
    const float cbd_l    = (bdp ? C[0][1] : C[1][1]) * bd;
    const float k_lbx    = fabsf(C[1][0] - C[0][0]);
    const float base_lbx = bdp ? C[1][0] : C[0][0];

    const float cbd_u    = (bdp ? C[3][1] : C[2][1]) * bd;
    const float k_ubx    = fabsf(C[2][0] - C[3][0]);
    const float base_ubx = bdp ? C[2][0] : C[3][0];

    const float cac_l    = (acp ? C[0][0] : C[3][0]) * ac;
    const float k_lby    = fabsf(C[0][1] - C[3][1]);
    const float base_lby = acp ? C[3][1] : C[0][1];

    const float cac_u    = (acp ? C[1][0] : C[2][0]) * ac;
    const float k_uby    = fabsf(C[1][1] - C[2][1]);
    const float base_uby = acp ? C[2][1] : C[1][1];

    const float Wi0 = w_input[0],  Wi1 = w_input[1];
    const float Wh0 = w_hidden[0], Wh1 = w_hidden[1];
    const float W10 = w_fc1[0],    W11 = w_fc1[1];
    const float W20 = w_fc2[0],    W21 = w_fc2[1];

    const size_t TB = (size_t)T * B;
    const float* px0 = xin  + b;
    const float* px1 = xin  + TB + b;
    const float* pr0 = rets + b;
    const float* pr1 = rets + TB + b;
    float* po0 = out + b;
    float* po1 = out + TB + b;

    // h0 = x[:,0,:]
    float hx = px0[0];
    float hy = px1[0];
    __builtin_nontemporal_store(hx, po0);
    __builtin_nontemporal_store(hy, po1);

    // one recurrence step: h <- cell(x, adjust(h, r)); store h at t
    auto step = [&](float x0, float x1, float r0, float r1, int t) {
        float denom = fmaf(hx, r0, fmaf(hy, r1, 1.0f));
        float inv   = __builtin_amdgcn_rcpf(denom);      // raw v_rcp_f32
        float nx    = fmaf(hx, r0, hx);                  // hx*(1+r0), off-chain
        float ny    = fmaf(hy, r1, hy);
        float adjx  = nx * inv;
        float adjy  = ny * inv;
        float lbx = base_lbx - fmaxf(k_lbx - fmaxf(fmaf(adjy, bd, -cbd_l), 0.0f), 0.0f);
        float ubx = base_ubx - fmaxf(k_ubx - fmaxf(fmaf(adjy, bd, -cbd_u), 0.0f), 0.0f);
        float lby = base_lby - fmaxf(k_lby - fmaxf(fmaf(adjx, ac, -cac_l), 0.0f), 0.0f);
        float uby = base_uby - fmaxf(k_uby - fmaxf(fmaf(adjx, ac, -cac_u), 0.0f), 0.0f);
        float pre0 = Wi0 * x0;                           // off-chain
        float pre1 = Wi1 * x1;
        float g1x = fmaxf(fmaf(Wh0, adjx, pre0) - lbx, 0.0f);
        float g1y = fmaxf(fmaf(Wh1, adjy, pre1) - lby, 0.0f);
        float g2x = fmaxf(fmaf(W10, g1x, ubx - lbx), 0.0f);
        float g2y = fmaxf(fmaf(W11, g1y, uby - lby), 0.0f);
        hx = fmaf(W20, g2x, ubx);
        hy = fmaf(W21, g2y, uby);
        __builtin_nontemporal_store(hx, po0 + (size_t)t * B);
        __builtin_nontemporal_store(hy, po1 + (size_t)t * B);
    };

#define LOADG(gx0, gx1, gr0, gr1, tb)                         \
    {                                                         \
        _Pragma("unroll")                                     \
        for (int i = 0; i < U; ++i) {                         \
            gx0[i] = px0[(size_t)((tb) + i) * B];             \
            gx1[i] = px1[(size_t)((tb) + i) * B];             \
            gr0[i] = pr0[(size_t)((tb) + i - 1) * B];         \
            gr1[i] = pr1[(size_t)((tb) + i - 1) * B];         \
        }                                                     \
    }

#define COMPUTEG(gx0, gx1, gr0, gr1, tb)                      \
    {                                                         \
        _Pragma("unroll")                                     \
        for (int i = 0; i < U; ++i)                           \
            step(gx0[i], gx1[i], gr0[i], gr1[i], (tb) + i);   \
    }

    if (T == 512) {
        // ---- depth-3 pipelined path: 7-step prologue + 63 groups of 8 ----
        float Ax0[U], Ax1[U], Ar0[U], Ar1[U];
        float Bx0[U], Bx1[U], Br0[U], Br1[U];
        float Cx0[U], Cx1[U], Cr0[U], Cr1[U];

        // prologue loads t=1..7
        float Px0[7], Px1[7], Pr0[7], Pr1[7];
#pragma unroll
        for (int i = 0; i < 7; ++i) {
            int t = 1 + i;
            Px0[i] = px0[(size_t)t * B];
            Px1[i] = px1[(size_t)t * B];
            Pr0[i] = pr0[(size_t)(t - 1) * B];
            Pr1[i] = pr1[(size_t)(t - 1) * B];
        }
        LOADG(Ax0, Ax1, Ar0, Ar1, 8);          // group 0 in flight

        // prologue compute t=1..7
#pragma unroll
        for (int i = 0; i < 7; ++i)
            step(Px0[i], Px1[i], Pr0[i], Pr1[i], 1 + i);

        LOADG(Bx0, Bx1, Br0, Br1, 16);         // group 1 in flight

        // main: 20 rounds x 3 phases = groups 0..59; each phase prefetches k+2
        int tc = 8;
        for (int r = 0; r < 20; ++r) {
            LOADG(Cx0, Cx1, Cr0, Cr1, tc + 16);
            COMPUTEG(Ax0, Ax1, Ar0, Ar1, tc);  tc += 8;
            LOADG(Ax0, Ax1, Ar0, Ar1, tc + 16);
            COMPUTEG(Bx0, Bx1, Br0, Br1, tc);  tc += 8;
            LOADG(Bx0, Bx1, Br0, Br1, tc + 16);
            COMPUTEG(Cx0, Cx1, Cr0, Cr1, tc);  tc += 8;
        }
        // tail: groups 60 (A, t=488), 61 (B, t=496), 62 (C, t=504)
        LOADG(Cx0, Cx1, Cr0, Cr1, 504);
        COMPUTEG(Ax0, Ax1, Ar0, Ar1, 488);
        COMPUTEG(Bx0, Bx1, Br0, Br1, 496);
        COMPUTEG(Cx0, Cx1, Cr0, Cr1, 504);
    } else {
        // generic fallback (simple, unpipelined)
        for (int t = 1; t < T; ++t) {
            float x0 = px0[(size_t)t * B];
            float x1 = px1[(size_t)t * B];
            float r0 = pr0[(size_t)(t - 1) * B];
            float r1 = pr1[(size_t)(t - 1) * B];
            step(x0, x1, r0, r1, t);
        }
    }

    // hT = last h, shape (2,1,B) appended after output
    __builtin_nontemporal_store(hx, out + 2 * TB + b);
    __builtin_nontemporal_store(hy, out + 2 * TB + B + b);
}

extern "C" void kernel_launch(void* const* d_in, const int* in_sizes, int n_in,
                              void* d_out, int out_size, void* d_ws, size_t ws_size,
                              hipStream_t stream) {
    const float* xin      = (const float*)d_in[0];
    const float* target   = (const float*)d_in[1];
    const float* rets     = (const float*)d_in[2];
    // d_in[3] = hidden (unused by reference)
    const float* w_input  = (const float*)d_in[4];
    const float* w_hidden = (const float*)d_in[5];
    const float* b_hidden = (const float*)d_in[6];
    const float* w_fc1    = (const float*)d_in[7];
    const float* w_fc2    = (const float*)d_in[8];
    const float* w_rotate = (const float*)d_in[9];
    float* out = (float*)d_out;

    const int B = in_sizes[3] / 2;             // hidden is (2,1,B)
    const int T = in_sizes[0] / in_sizes[3];   // input is (2,T,B)

    const int threads = 64;
    const int blocks  = (B + threads - 1) / threads;
    hipLaunchKernelGGL(ntr_rnn_kernel, dim3(blocks), dim3(threads), 0, stream,
                       xin, target, rets, w_input, w_hidden, b_hidden,
                       w_fc1, w_fc2, w_rotate, out, T, B);
}